// Round 8
// baseline (120.368 us; speedup 1.0000x reference)
//
#include <hip/hip_runtime.h>
#include <math.h>

// EnhancedFinancialGAT — analytical collapse (Round 0 proof: all N=2000 node
// rows identical + per-dst softmax sums to 1 (self-loop guarantees denom>=1)
// => each GAT layer is a dense 256->256 relu; edges/attention irrelevant).
//
// Round 8: single-dispatch, fp32 weights, split-half register pipelining.
// R5 (fp16 bytes) and R7 (fp16 acts + fdot2) were neutral => not byte/issue
// bound; the removable cost is the compress_w prepass dispatch + gap (~9 us).
// Dropping fp16 needs fp32 frags (2x VGPRs), so prefetch depth is halved:
// per layer: issue H2(l) -> compute H1(l) -> issue H1(l+1) -> compute H2(l).
// Peak live ~96-105 VGPR < 128 cap (1024-thread block). Biases in LDS,
// final dot weights preloaded (R6). Pure fp32 accuracy (~2.4e-4).

#define B_ITEMS 64

// ---- bias layout in LDS (float offsets) ----
#define BIN   0
#define BGAT  256
#define BFUSE 1024
#define BP1   1280
#define BD1   1408
#define BP2   1536
#define BD2   1600
#define NBIAS 1664

// Half of one lane's K-slice of its output row: K/(8G) float4s.
template <int K, int G>
struct HFrag { float4 w[K / (8 * G)]; };

template <int K, int G, int HALF>
__device__ __forceinline__ void load_halfw(HFrag<K, G>& f,
                                           const float* __restrict__ W, int t) {
    const int c = t & (G - 1);
    const int o = t / G;
    const float4* __restrict__ W4 =
        reinterpret_cast<const float4*>(W + (size_t)o * K);
    constexpr int NC = K / (8 * G);
#pragma unroll
    for (int j = 0; j < NC; ++j) f.w[j] = W4[(HALF * NC + j) * G + c];
}

template <int K, int G, int HALF>
__device__ __forceinline__ float dot_halfw(const HFrag<K, G>& f,
                                           const float* __restrict__ in,  // LDS
                                           int t, float acc) {
    const int c = t & (G - 1);
    const float4* __restrict__ A4 = reinterpret_cast<const float4*>(in);
    constexpr int NC = K / (8 * G);
#pragma unroll
    for (int j = 0; j < NC; ++j) {
        float4 a = A4[(HALF * NC + j) * G + c];
        float4 w = f.w[j];
        acc = fmaf(w.x, a.x, acc);
        acc = fmaf(w.y, a.y, acc);
        acc = fmaf(w.z, a.z, acc);
        acc = fmaf(w.w, a.w, acc);
    }
    return acc;
}

template <int G>
__device__ __forceinline__ void red_store(float acc, const float* __restrict__ bias,
                                          float* __restrict__ out, int t) {
    const int c = t & (G - 1);
    const int o = t / G;
#pragma unroll
    for (int s = 1; s < G; s <<= 1) acc += __shfl_xor(acc, s, 64);
    if (c == 0) out[o] = fmaxf(acc + bias[o], 0.f);
}

extern "C" __global__ __launch_bounds__(1024) void fin_gat_v8(
    const float* __restrict__ x,        // [64,64]
    const int* __restrict__ cidx,       // [64]
    const float* __restrict__ W_in,     // [256,64]
    const float* __restrict__ b_in,
    const float* __restrict__ gat_W,    // [3,256,256]
    const float* __restrict__ gat_b,    // [3,256]
    const float* __restrict__ emb,      // [2000,64]
    const float* __restrict__ W_fuse,   // [256,320]
    const float* __restrict__ b_fuse,
    const float* __restrict__ W_p1, const float* __restrict__ b_p1,  // [128,256]
    const float* __restrict__ W_p2, const float* __restrict__ b_p2,  // [64,128]
    const float* __restrict__ W_p3, const float* __restrict__ b_p3,  // [1,64]
    const float* __restrict__ W_d1, const float* __restrict__ b_d1,
    const float* __restrict__ W_d2, const float* __restrict__ b_d2,
    const float* __restrict__ W_d3, const float* __restrict__ b_d3,
    float* __restrict__ out)            // [128]
{
    __shared__ __align__(16) float bufA[320];
    __shared__ __align__(16) float bufB[320];
    __shared__ float bias_lds[NBIAS];

    const int b = blockIdx.x;
    const int t = threadIdx.x;

    // ---- initial burst: L0 weights (full), L1 first half, x/emb, biases ----
    HFrag<64, 4> f_in_a, f_in_b;            // W_in, 2+2 float4
    load_halfw<64, 4, 0>(f_in_a, W_in, t);
    load_halfw<64, 4, 1>(f_in_b, W_in, t);
    HFrag<256, 4> g0a;                      // gat_W0 H1 (8 float4)
    load_halfw<256, 4, 0>(g0a, gat_W, t);

    if (t < 64) {
        const int ci = cidx[b];
        bufA[t] = x[b * 64 + t];
        bufA[256 + t] = emb[(size_t)ci * 64 + t];   // kept for fuse layer
    }
    float wdot = 0.f, bdot = 0.f;
    if (t < 64)            wdot = W_p3[t];
    else if (t < 128)      wdot = W_d3[t - 64];
    if (t == 0)            bdot = b_p3[0];
    else if (t == 64)      bdot = b_d3[0];

#pragma unroll
    for (int i = t; i < NBIAS; i += 1024) {
        float v;
        if      (i < 256)  v = b_in[i];
        else if (i < 1024) v = gat_b[i - 256];
        else if (i < 1280) v = b_fuse[i - 1024];
        else if (i < 1408) v = b_p1[i - 1280];
        else if (i < 1536) v = b_d1[i - 1408];
        else if (i < 1600) v = b_p2[i - 1536];
        else               v = b_d2[i - 1600];
        bias_lds[i] = v;
    }
    __syncthreads();

    // ---- L0: h = relu(W_in x): A[0:64] -> B[0:256] ----
    HFrag<256, 4> g0b;
    load_halfw<256, 4, 1>(g0b, gat_W, t);               // issue gat0 H2
    {
        float acc = dot_halfw<64, 4, 0>(f_in_a, bufA, t, 0.f);
        acc = dot_halfw<64, 4, 1>(f_in_b, bufA, t, acc);
        red_store<4>(acc, bias_lds + BIN, bufB, t);
    }
    __syncthreads();

    // ---- L1 (GAT1): B -> A[0:256]  (emb intact in A[256:320]) ----
    HFrag<256, 4> g1a;
    load_halfw<256, 4, 0>(g1a, gat_W + 1 * 65536, t);   // issue gat1 H1
    {
        float acc = dot_halfw<256, 4, 0>(g0a, bufB, t, 0.f);
        acc = dot_halfw<256, 4, 1>(g0b, bufB, t, acc);
        red_store<4>(acc, bias_lds + BGAT, bufA, t);
    }
    __syncthreads();

    // ---- L2 (GAT2): A -> B ----
    HFrag<256, 4> g1b;
    load_halfw<256, 4, 1>(g1b, gat_W + 1 * 65536, t);   // issue gat1 H2
    {
        float acc = dot_halfw<256, 4, 0>(g1a, bufA, t, 0.f);
        HFrag<256, 4> g2a;
        load_halfw<256, 4, 0>(g2a, gat_W + 2 * 65536, t);  // issue gat2 H1
        acc = dot_halfw<256, 4, 1>(g1b, bufA, t, acc);
        red_store<4>(acc, bias_lds + BGAT + 256, bufB, t);
        __syncthreads();

        // ---- L3 (GAT3): B -> A[0:256] ----
        HFrag<256, 4> g2b;
        load_halfw<256, 4, 1>(g2b, gat_W + 2 * 65536, t);  // issue gat2 H2
        float acc3 = dot_halfw<256, 4, 0>(g2a, bufB, t, 0.f);
        HFrag<320, 4> fua;
        load_halfw<320, 4, 0>(fua, W_fuse, t);             // issue fuse H1
        acc3 = dot_halfw<256, 4, 1>(g2b, bufB, t, acc3);
        red_store<4>(acc3, bias_lds + BGAT + 512, bufA, t);
        __syncthreads();

        // ---- L4 (fuse): A[0:320] -> B[0:256] ----
        HFrag<320, 4> fub;
        load_halfw<320, 4, 1>(fub, W_fuse, t);             // issue fuse H2
        float acc4 = dot_halfw<320, 4, 0>(fua, bufA, t, 0.f);
        const float* Wh1 = (t < 512) ? W_p1 : W_d1;
        const int tl = t & 511;
        HFrag<256, 4> h1a;
        load_halfw<256, 4, 0>(h1a, Wh1, tl);               // issue heads-1 H1
        acc4 = dot_halfw<320, 4, 1>(fub, bufA, t, acc4);
        red_store<4>(acc4, bias_lds + BFUSE, bufB, t);
        __syncthreads();

        // ---- L5: p1 (lower half-block) / d1 (upper half-block) ----
        HFrag<256, 4> h1b;
        load_halfw<256, 4, 1>(h1b, Wh1, tl);               // issue heads-1 H2
        float acc5 = dot_halfw<256, 4, 0>(h1a, bufB, tl, 0.f);
        const float* Wh2 = (t < 512) ? W_p2 : W_d2;
        HFrag<128, 8> h2a, h2b;
        load_halfw<128, 8, 0>(h2a, Wh2, tl);               // issue heads-2 (full)
        load_halfw<128, 8, 1>(h2b, Wh2, tl);
        acc5 = dot_halfw<256, 4, 1>(h1b, bufB, tl, acc5);
        {
            float* dst = (t < 512) ? bufA : bufA + 192;
            const float* bs = (t < 512) ? bias_lds + BP1 : bias_lds + BD1;
            red_store<4>(acc5, bs, dst, tl);
        }
        __syncthreads();

        // ---- L6: p2 / d2 ----
        {
            const float* src = (t < 512) ? bufA : bufA + 192;
            float* dst = (t < 512) ? bufB : bufB + 64;
            const float* bs = (t < 512) ? bias_lds + BP2 : bias_lds + BD2;
            float acc6 = dot_halfw<128, 8, 0>(h2a, src, tl, 0.f);
            acc6 = dot_halfw<128, 8, 1>(h2b, src, tl, acc6);
            red_store<8>(acc6, bs, dst, tl);
        }
        __syncthreads();
    }

    // ---- final dots (weights preloaded): wave 0 -> price, wave 1 -> dir ----
    if (t < 64) {
        float v = wdot * bufB[t];
#pragma unroll
        for (int off = 32; off > 0; off >>= 1) v += __shfl_down(v, off, 64);
        if (t == 0) out[b] = v + bdot;
    } else if (t < 128) {
        const int u = t - 64;
        float v = wdot * bufB[64 + u];
#pragma unroll
        for (int off = 32; off > 0; off >>= 1) v += __shfl_down(v, off, 64);
        if (u == 0) {
            float z = v + bdot;
            out[B_ITEMS + b] = 1.0f / (1.0f + expf(-z));
        }
    }
}

extern "C" void kernel_launch(void* const* d_in, const int* in_sizes, int n_in,
                              void* d_out, int out_size, void* d_ws, size_t ws_size,
                              hipStream_t stream) {
    const float* x      = (const float*)d_in[0];
    const int*   cidx   = (const int*)  d_in[1];
    // d_in[2]=edge_index, d_in[3]=edge_attr -> numerically irrelevant
    const float* W_in   = (const float*)d_in[4];
    const float* b_in   = (const float*)d_in[5];
    const float* gat_W  = (const float*)d_in[6];
    // d_in[7..10] = att params -> irrelevant
    const float* gat_b  = (const float*)d_in[11];
    const float* emb    = (const float*)d_in[12];
    const float* W_fuse = (const float*)d_in[13];
    const float* b_fuse = (const float*)d_in[14];
    const float* W_p1   = (const float*)d_in[15];
    const float* b_p1   = (const float*)d_in[16];
    const float* W_p2   = (const float*)d_in[17];
    const float* b_p2   = (const float*)d_in[18];
    const float* W_p3   = (const float*)d_in[19];
    const float* b_p3   = (const float*)d_in[20];
    const float* W_d1   = (const float*)d_in[21];
    const float* b_d1   = (const float*)d_in[22];
    const float* W_d2   = (const float*)d_in[23];
    const float* b_d2   = (const float*)d_in[24];
    const float* W_d3   = (const float*)d_in[25];
    const float* b_d3   = (const float*)d_in[26];

    fin_gat_v8<<<B_ITEMS, 1024, 0, stream>>>(
        x, cidx, W_in, b_in, gat_W, gat_b, emb, W_fuse, b_fuse,
        W_p1, b_p1, W_p2, b_p2, W_p3, b_p3,
        W_d1, b_d1, W_d2, b_d2, W_d3, b_d3,
        (float*)d_out);
}